// Round 2
// baseline (462.021 us; speedup 1.0000x reference)
//
#include <hip/hip_runtime.h>

__device__ __forceinline__ float sigmoid_f(float x) {
  return 1.0f / (1.0f + __expf(-x));
}

// =====================================================================
// K1: 3x3 conv, 128->128 ch, pad 1, fp32.
// grid 512 = b(2) * h(128) * cohalf(2); block 256.
// thread: wi = tid&7 -> 16 consecutive w; col = tid>>3 -> co pair (col, col+32).
// =====================================================================
__global__ __launch_bounds__(256) void conv3x3_k(
    const float* __restrict__ x, const float* __restrict__ cw,
    const float* __restrict__ cb, float* __restrict__ y) {
  __shared__ float xs[16 * 3 * 132];   // [ci][dh][w], w-pad cols 128..131

  const int tid  = threadIdx.x;
  const int bid  = blockIdx.x;
  const int half = bid & 1;
  const int h    = (bid >> 1) & 127;
  const int b    = bid >> 8;

  const int wi  = tid & 7;
  const int col = tid >> 3;          // 0..31
  const int w0  = wi * 16;
  const int coA = half * 64 + col;
  const int coB = coA + 32;

  float accA[16], accB[16];
  const float bA = cb[coA];
  const float bB = cb[coB];
#pragma unroll
  for (int i = 0; i < 16; ++i) { accA[i] = bA; accB[i] = bB; }

  for (int cit = 0; cit < 8; ++cit) {
    const int ci0 = cit * 16;
    __syncthreads();
    // zero the w-pads (index 128 of each of 48 rows; 129-131 never read)
    if (tid < 48) xs[tid * 132 + 128] = 0.f;
    // stage x[b, ci0..ci0+15, h-1..h+1, 0..127] as float4 loads (6/thread)
#pragma unroll
    for (int r = 0; r < 6; ++r) {
      int li  = r * 256 + tid;         // 0..1535 quad index
      int ci  = li / 96;
      int rem = li - ci * 96;
      int dh  = rem >> 5;
      int wq  = rem & 31;
      int hh  = h + dh - 1;
      float4 v = make_float4(0.f, 0.f, 0.f, 0.f);
      if (hh >= 0 && hh < 128) {
        v = ((const float4*)(x + (size_t)(((b * 128 + ci0 + ci) * 128 + hh) * 128)))[wq];
      }
      *(float4*)&xs[(ci * 3 + dh) * 132 + wq * 4] = v;
    }
    __syncthreads();

    for (int ci = 0; ci < 16; ++ci) {
      float wA[9], wB[9];
      const float* pwA = cw + (size_t)(coA * 128 + ci0 + ci) * 9;
      const float* pwB = cw + (size_t)(coB * 128 + ci0 + ci) * 9;
#pragma unroll
      for (int t = 0; t < 9; ++t) { wA[t] = pwA[t]; wB[t] = pwB[t]; }
#pragma unroll
      for (int kh = 0; kh < 3; ++kh) {
        const float* row = &xs[(ci * 3 + kh) * 132];
        float xw[18];
        {
          int off = (wi == 0) ? 0 : (w0 - 1);
          float v = row[off];
          xw[0] = (wi == 0) ? 0.f : v;
        }
#pragma unroll
        for (int q = 0; q < 4; ++q) {
          float4 v = *(const float4*)&row[w0 + q * 4];
          xw[1 + q * 4] = v.x; xw[2 + q * 4] = v.y;
          xw[3 + q * 4] = v.z; xw[4 + q * 4] = v.w;
        }
        xw[17] = row[w0 + 16];   // wi==7 hits zeroed pad
#pragma unroll
        for (int kw = 0; kw < 3; ++kw) {
          const float fA = wA[kh * 3 + kw];
          const float fB = wB[kh * 3 + kw];
#pragma unroll
          for (int ww = 0; ww < 16; ++ww) {
            accA[ww] = fmaf(fA, xw[ww + kw], accA[ww]);
            accB[ww] = fmaf(fB, xw[ww + kw], accB[ww]);
          }
        }
      }
    }
  }
  float* yA = y + (size_t)(((b * 128 + coA) * 128 + h) * 128 + w0);
  float* yB = y + (size_t)(((b * 128 + coB) * 128 + h) * 128 + w0);
#pragma unroll
  for (int q = 0; q < 4; ++q) {
    *(float4*)&yA[q * 4] = make_float4(accA[q*4], accA[q*4+1], accA[q*4+2], accA[q*4+3]);
    *(float4*)&yB[q * 4] = make_float4(accB[q*4], accB[q*4+1], accB[q*4+2], accB[q*4+3]);
  }
}

// =====================================================================
// K2: Mamba over 32768 sequences (one per (b,c,h) row; L=8 tokens x 16 dim).
// 8 sequences/block, thread = (s = tid>>5, ch = tid&31 -> d_inner channel).
// Writes out_proj result m into d_out (staging); accumulates GroupNorm
// sum/sumsq (one (b,group) per block) into stats.
// =====================================================================
__global__ __launch_bounds__(256) void mamba_k(
    const float* __restrict__ y,
    const float* __restrict__ w_in,   // (64,16)
    const float* __restrict__ c1w,    // (32,1,4)
    const float* __restrict__ c1b,    // (32)
    const float* __restrict__ xpw,    // (33,32)
    const float* __restrict__ dtw,    // (32,1)
    const float* __restrict__ dtb,    // (32)
    const float* __restrict__ alog,   // (32,16)
    const float* __restrict__ dvec,   // (32)
    const float* __restrict__ wout,   // (16,32)
    float* __restrict__ m, float* __restrict__ stats) {
  __shared__ float Wi_t[16 * 64];      // [d][e]
  __shared__ float Xp_t[32 * 33];      // [d][j]
  __shared__ float A2_s[32 * 17];      // [ch][st] pad17: -exp(A_log)*log2e
  __shared__ float Wo_t[32 * 17];      // [d][e] pad17
  __shared__ float c1w_s[128], c1b_s[32], dtw_s[32], dtb_s[32], D_s[32];
  __shared__ float ylds[8 * 128];
  __shared__ float xc_s[64 * 32];
  __shared__ float dt0_s[64];
  __shared__ float B_s[64 * 16];
  __shared__ float C_s[64 * 16];
  __shared__ float ym_s[64 * 32];
  __shared__ float red_s[8];

  const int tid = threadIdx.x;
  for (int i = tid; i < 1024; i += 256) {
    int e = i >> 4, d = i & 15;
    Wi_t[d * 64 + e] = w_in[i];
  }
  for (int i = tid; i < 1056; i += 256) {
    int e = i >> 5, d = i & 31;
    Xp_t[d * 33 + e] = xpw[i];
  }
  for (int i = tid; i < 512; i += 256) {
    int ch = i >> 4, st = i & 15;
    A2_s[ch * 17 + st] = -__expf(alog[i]) * 1.44269504088896f;
    int e2 = i >> 5, d2 = i & 31;
    Wo_t[d2 * 17 + e2] = wout[i];
  }
  if (tid < 128) c1w_s[tid] = c1w[tid];
  if (tid < 32) {
    c1b_s[tid] = c1b[tid];
    dtw_s[tid] = dtw[tid];
    dtb_s[tid] = dtb[tid];
    D_s[tid]   = dvec[tid];
  }
  {
    const float4* src = (const float4*)(y + (size_t)blockIdx.x * 1024);
    *(float4*)&ylds[tid * 4] = src[tid];
  }
  __syncthreads();

  const int s  = tid >> 5;
  const int ch = tid & 31;
  const float* yr = &ylds[s * 128];

  // in_proj: xi (e=ch), z (e=ch+32)
  float xi[8], zg[8];
#pragma unroll
  for (int l = 0; l < 8; ++l) {
    float ax = 0.f, az = 0.f;
#pragma unroll
    for (int d = 0; d < 16; ++d) {
      float sv = yr[l * 16 + d];
      ax = fmaf(sv, Wi_t[d * 64 + ch], ax);
      az = fmaf(sv, Wi_t[d * 64 + 32 + ch], az);
    }
    xi[l] = ax; zg[l] = az;
  }
  // causal depthwise conv1d (k=4) + SiLU
  float cwr[4];
#pragma unroll
  for (int k = 0; k < 4; ++k) cwr[k] = c1w_s[ch * 4 + k];
  const float cbr = c1b_s[ch];
  float xc[8];
#pragma unroll
  for (int l = 0; l < 8; ++l) {
    float a = fmaf(cwr[3], xi[l], cbr);
    if (l >= 1) a = fmaf(cwr[2], xi[l - 1], a);
    if (l >= 2) a = fmaf(cwr[1], xi[l - 2], a);
    if (l >= 3) a = fmaf(cwr[0], xi[l - 3], a);
    float sc = a * sigmoid_f(a);
    xc[l] = sc;
    xc_s[(s * 8 + l) * 32 + ch] = sc;
  }
  __syncthreads();
  // x_proj: j = ch (thread ch==0 also does j=32)
#pragma unroll
  for (int l = 0; l < 8; ++l) {
    const float* xr = &xc_s[(s * 8 + l) * 32];
    float a = 0.f;
#pragma unroll
    for (int d = 0; d < 32; ++d) a = fmaf(xr[d], Xp_t[d * 33 + ch], a);
    if (ch == 0)        dt0_s[s * 8 + l] = a;
    else if (ch <= 16)  B_s[(s * 8 + l) * 16 + (ch - 1)]  = a;
    else                C_s[(s * 8 + l) * 16 + (ch - 17)] = a;
    if (ch == 0) {
      float a2 = 0.f;
#pragma unroll
      for (int d = 0; d < 32; ++d) a2 = fmaf(xr[d], Xp_t[d * 33 + 32], a2);
      C_s[(s * 8 + l) * 16 + 15] = a2;
    }
  }
  __syncthreads();
  // selective scan
  float A2r[16];
#pragma unroll
  for (int st = 0; st < 16; ++st) A2r[st] = A2_s[ch * 17 + st];
  const float dwv = dtw_s[ch], dbv = dtb_s[ch], Dv = D_s[ch];
  float hreg[16];
#pragma unroll
  for (int st = 0; st < 16; ++st) hreg[st] = 0.f;
#pragma unroll
  for (int l = 0; l < 8; ++l) {
    float pre = fmaf(dt0_s[s * 8 + l], dwv, dbv);
    float dtl = (pre > 20.f) ? pre : log1pf(__expf(pre));   // softplus
    float dtxc = dtl * xc[l];
    const float* Br = &B_s[(s * 8 + l) * 16];
    const float* Cr = &C_s[(s * 8 + l) * 16];
    float yl = 0.f;
#pragma unroll
    for (int st = 0; st < 16; ++st) {
      float aa = exp2f(dtl * A2r[st]);      // exp(dt*A) via pre-scaled A
      float bb = dtxc * Br[st];
      hreg[st] = fmaf(aa, hreg[st], bb);
      yl = fmaf(hreg[st], Cr[st], yl);
    }
    float ymv = fmaf(Dv, xc[l], yl) * (zg[l] * sigmoid_f(zg[l]));
    ym_s[(s * 8 + l) * 32 + ch] = ymv;
  }
  __syncthreads();
  // out_proj: thread -> e = ch&15, l-group = ch>>4 (4 l each)
  const int e  = ch & 15;
  const int lg = ch >> 4;
  const int n  = blockIdx.x * 8 + s;
  float ls = 0.f, lq = 0.f;
  float* mrow = m + (size_t)n * 128;
#pragma unroll
  for (int i = 0; i < 4; ++i) {
    int l = lg * 4 + i;
    const float* ymr = &ym_s[(s * 8 + l) * 32];
    float a = 0.f;
#pragma unroll
    for (int d = 0; d < 32; ++d) a = fmaf(ymr[d], Wo_t[d * 17 + e], a);
    mrow[l * 16 + e] = a;
    ls += a;
    lq = fmaf(a, a, lq);
  }
  // block reduce for GroupNorm stats (whole block is one (b, group))
#pragma unroll
  for (int off = 32; off > 0; off >>= 1) {
    ls += __shfl_down(ls, off);
    lq += __shfl_down(lq, off);
  }
  const int wid = tid >> 6;
  if ((tid & 63) == 0) { red_s[wid * 2] = ls; red_s[wid * 2 + 1] = lq; }
  __syncthreads();
  if (tid == 0) {
    float S = red_s[0] + red_s[2] + red_s[4] + red_s[6];
    float Q = red_s[1] + red_s[3] + red_s[5] + red_s[7];
    int bb = n >> 14;
    int cc = (n >> 7) & 127;
    int gg = cc >> 5;
    atomicAdd(&stats[(bb * 4 + gg) * 2 + 0], S);
    atomicAdd(&stats[(bb * 4 + gg) * 2 + 1], Q);
  }
}

// =====================================================================
// K3: GroupNorm finalize + SiLU + residual, fp32, in-place on d_out
// (m was staged there by K2). 4 elems/thread.
// =====================================================================
__global__ __launch_bounds__(256) void gn_silu_k(
    const float* __restrict__ x,
    const float* __restrict__ gnw, const float* __restrict__ gnb,
    const float* __restrict__ stats, float* __restrict__ out) {
  const int idx0 = (blockIdx.x * 256 + threadIdx.x) * 4;
  const int bb = idx0 >> 21;
  const int cc = (idx0 >> 14) & 127;
  const int gg = cc >> 5;
  const float S = stats[(bb * 4 + gg) * 2 + 0];
  const float Q = stats[(bb * 4 + gg) * 2 + 1];
  const float inv  = 1.0f / 524288.0f;
  const float mu   = S * inv;
  const float var  = fmaf(Q, inv, -mu * mu);
  const float rstd = rsqrtf(var + 1e-5f);
  const float gw  = gnw[cc] * rstd;
  const float gb2 = gnb[cc] - mu * gw;

  float4 mv = *(const float4*)(out + idx0);     // staged m
  float4 xv = *(const float4*)(x + idx0);
  float mvv[4] = { mv.x, mv.y, mv.z, mv.w };
  float xf[4]  = { xv.x, xv.y, xv.z, xv.w };
  float res[4];
#pragma unroll
  for (int j = 0; j < 4; ++j) {
    float nv = fmaf(mvv[j], gw, gb2);
    float sv = nv * sigmoid_f(nv);
    res[j] = xf[j] + sv;
  }
  *(float4*)(out + idx0) = make_float4(res[0], res[1], res[2], res[3]);
}

// =====================================================================
extern "C" void kernel_launch(void* const* d_in, const int* in_sizes, int n_in,
                              void* d_out, int out_size, void* d_ws, size_t ws_size,
                              hipStream_t stream) {
  const float* x     = (const float*)d_in[0];
  const float* convw = (const float*)d_in[1];
  const float* convb = (const float*)d_in[2];
  const float* gnw   = (const float*)d_in[3];
  const float* gnb   = (const float*)d_in[4];
  const float* winp  = (const float*)d_in[5];
  const float* c1w   = (const float*)d_in[6];
  const float* c1b   = (const float*)d_in[7];
  const float* xpw   = (const float*)d_in[8];
  const float* dtw   = (const float*)d_in[9];
  const float* dtb   = (const float*)d_in[10];
  const float* alog  = (const float*)d_in[11];
  const float* dvec  = (const float*)d_in[12];
  const float* wout  = (const float*)d_in[13];

  float* y     = (float*)d_ws;                 // 4,194,304 f32 (16 MB)
  float* stats = y + 4194304;                  // 16 f32
  float* m     = (float*)d_out;                // staged in d_out, finalized in place

  hipMemsetAsync(stats, 0, 16 * sizeof(float), stream);
  hipLaunchKernelGGL(conv3x3_k, dim3(512), dim3(256), 0, stream, x, convw, convb, y);
  hipLaunchKernelGGL(mamba_k, dim3(4096), dim3(256), 0, stream,
                     y, winp, c1w, c1b, xpw, dtw, dtb, alog, dvec, wout, m, stats);
  hipLaunchKernelGGL(gn_silu_k, dim3(4096), dim3(256), 0, stream,
                     x, gnw, gnb, stats, (float*)d_out);
}

// Round 3
// 291.204 us; speedup vs baseline: 1.5866x; 1.5866x over previous
//
#include <hip/hip_runtime.h>

typedef unsigned short USHORT;
typedef short short8 __attribute__((ext_vector_type(8)));
typedef float f32x4 __attribute__((ext_vector_type(4)));

__device__ __forceinline__ float sigmoid_f(float x) {
  return 1.0f / (1.0f + __expf(-x));
}
__device__ __forceinline__ USHORT f2b(float f) {   // fp32 -> bf16 RNE
  unsigned int u = __float_as_uint(f);
  unsigned int r = (u + 0x7fffu + ((u >> 16) & 1u)) >> 16;
  return (USHORT)r;
}

// =====================================================================
// K0: repack conv weights (co,ci,3,3) fp32 -> Wrep[kk][co][ci] bf16.
// =====================================================================
__global__ __launch_bounds__(256) void prep_w_k(
    const float* __restrict__ cw, USHORT* __restrict__ wrep) {
  const int idx = blockIdx.x * 256 + threadIdx.x;   // 0..147455
  const int kk = idx >> 14;
  const int co = (idx >> 7) & 127;
  const int ci = idx & 127;
  wrep[idx] = f2b(cw[(co * 128 + ci) * 9 + kk]);
}

// =====================================================================
// K1: 3x3 conv as implicit-GEMM MFMA (bf16 in, fp32 acc).
// grid 512 = wh(2) * h(128) * b(2); block 256 (4 waves).
// Block tile: 128 co x 64 w at fixed (b,h). K = 4 chunks of 32 ci x 9 taps.
// Wave: 64 co x 32 w = 4 co-strips x 2 w-subtiles (16x16x32 MFMA).
// =====================================================================
__global__ __launch_bounds__(256) void conv_mfma_k(
    const float* __restrict__ x, const USHORT* __restrict__ wrep,
    const float* __restrict__ cb, float* __restrict__ y) {
  // xt[dh 3][wl 72][ci 32 pad 40] bf16 : 17280 B
  __shared__ USHORT xt[3 * 72 * 40];

  const int tid = threadIdx.x;
  const int bid = blockIdx.x;
  const int wh  = bid & 1;
  const int h   = (bid >> 1) & 127;
  const int b   = bid >> 8;
  const int w0  = wh * 64;

  const int wv   = tid >> 6;          // wave 0..3
  const int lane = tid & 63;
  const int m    = lane & 15;         // MFMA m / n / C-col index
  const int kg   = lane >> 4;         // quad: k-group (A/B), row-group (C)
  const int co0w = (wv & 1) * 64;     // wave's co base
  const int ws0  = (wv >> 1) * 32;    // wave's w base (within 64-w tile)

  f32x4 acc[4][2];
#pragma unroll
  for (int s = 0; s < 4; ++s)
#pragma unroll
    for (int ws = 0; ws < 2; ++ws) acc[s][ws] = (f32x4){0.f, 0.f, 0.f, 0.f};

  // invariant pieces of frag addresses
  const USHORT* wrow = wrep + (co0w + m) * 128 + kg * 8;       // + t9*16384 + s*2048 + ci0
  const int xb = (ws0 + 3 + m) * 40 + kg * 8;                  // + kh*2880 + (kw+ws*16)*40

  for (int c = 0; c < 4; ++c) {
    const int ci0 = c * 32;
    __syncthreads();
    // ---- stage x[b, ci0..ci0+31, h-1..h+1, w0-4..w0+67] -> bf16 xt ----
    // 1728 tasks: (dh 3) x (ciq 8) x (wl 72); task = grp*72 + wl
#pragma unroll
    for (int it = 0; it < 7; ++it) {
      int task = it * 256 + tid;
      if (task < 1728) {
        int grp = task / 72;
        int wl  = task - grp * 72;
        int ciq = grp & 7;
        int dh  = grp >> 3;
        int wg  = w0 - 4 + wl;
        int hh  = h + dh - 1;
        bool ok = ((unsigned)wg < 128u) && ((unsigned)hh < 128u);
        float v0 = 0.f, v1 = 0.f, v2 = 0.f, v3 = 0.f;
        if (ok) {
          const float* p = x + ((size_t)((b * 128 + ci0 + ciq * 4) * 128 + hh)) * 128 + wg;
          v0 = p[0];
          v1 = p[16384];
          v2 = p[32768];
          v3 = p[49152];
        }
        unsigned int lo = (unsigned int)f2b(v0) | ((unsigned int)f2b(v1) << 16);
        unsigned int hi = (unsigned int)f2b(v2) | ((unsigned int)f2b(v3) << 16);
        *(uint2*)&xt[(dh * 72 + wl) * 40 + ciq * 4] = make_uint2(lo, hi);
      }
    }
    __syncthreads();

    // ---- MFMA over 9 taps ----
#pragma unroll
    for (int t9 = 0; t9 < 9; ++t9) {
      const int kh = t9 / 3, kw = t9 - kh * 3;
      short8 a[4];
#pragma unroll
      for (int s = 0; s < 4; ++s)
        a[s] = *(const short8*)(wrow + t9 * 16384 + s * 2048 + ci0);
#pragma unroll
      for (int ws = 0; ws < 2; ++ws) {
        short8 bf = *(const short8*)&xt[xb + kh * 2880 + (kw + ws * 16) * 40];
#pragma unroll
        for (int s = 0; s < 4; ++s)
          acc[s][ws] = __builtin_amdgcn_mfma_f32_16x16x32_bf16(a[s], bf, acc[s][ws], 0, 0, 0);
      }
    }
  }

  // ---- epilogue: bias + store fp32 y ----
  float biasv[16];
#pragma unroll
  for (int s = 0; s < 4; ++s)
#pragma unroll
    for (int r = 0; r < 4; ++r)
      biasv[s * 4 + r] = cb[co0w + s * 16 + kg * 4 + r];
#pragma unroll
  for (int s = 0; s < 4; ++s) {
#pragma unroll
    for (int ws = 0; ws < 2; ++ws) {
      const int w = w0 + ws0 + ws * 16 + m;
#pragma unroll
      for (int r = 0; r < 4; ++r) {
        const int co = co0w + s * 16 + kg * 4 + r;
        y[((size_t)((b * 128 + co) * 128 + h)) * 128 + w] = acc[s][ws][r] + biasv[s * 4 + r];
      }
    }
  }
}

// =====================================================================
// K2: Mamba over 32768 sequences (unchanged from R2).
// =====================================================================
__global__ __launch_bounds__(256) void mamba_k(
    const float* __restrict__ y,
    const float* __restrict__ w_in, const float* __restrict__ c1w,
    const float* __restrict__ c1b, const float* __restrict__ xpw,
    const float* __restrict__ dtw, const float* __restrict__ dtb,
    const float* __restrict__ alog, const float* __restrict__ dvec,
    const float* __restrict__ wout,
    float* __restrict__ m, float* __restrict__ stats) {
  __shared__ float Wi_t[16 * 64];
  __shared__ float Xp_t[32 * 33];
  __shared__ float A2_s[32 * 17];
  __shared__ float Wo_t[32 * 17];
  __shared__ float c1w_s[128], c1b_s[32], dtw_s[32], dtb_s[32], D_s[32];
  __shared__ float ylds[8 * 128];
  __shared__ float xc_s[64 * 32];
  __shared__ float dt0_s[64];
  __shared__ float B_s[64 * 16];
  __shared__ float C_s[64 * 16];
  __shared__ float ym_s[64 * 32];
  __shared__ float red_s[8];

  const int tid = threadIdx.x;
  for (int i = tid; i < 1024; i += 256) {
    int e = i >> 4, d = i & 15;
    Wi_t[d * 64 + e] = w_in[i];
  }
  for (int i = tid; i < 1056; i += 256) {
    int e = i >> 5, d = i & 31;
    Xp_t[d * 33 + e] = xpw[i];
  }
  for (int i = tid; i < 512; i += 256) {
    int ch = i >> 4, st = i & 15;
    A2_s[ch * 17 + st] = -__expf(alog[i]) * 1.44269504088896f;
    int e2 = i >> 5, d2 = i & 31;
    Wo_t[d2 * 17 + e2] = wout[i];
  }
  if (tid < 128) c1w_s[tid] = c1w[tid];
  if (tid < 32) {
    c1b_s[tid] = c1b[tid];
    dtw_s[tid] = dtw[tid];
    dtb_s[tid] = dtb[tid];
    D_s[tid]   = dvec[tid];
  }
  {
    const float4* src = (const float4*)(y + (size_t)blockIdx.x * 1024);
    *(float4*)&ylds[tid * 4] = src[tid];
  }
  __syncthreads();

  const int s  = tid >> 5;
  const int ch = tid & 31;
  const float* yr = &ylds[s * 128];

  float xi[8], zg[8];
#pragma unroll
  for (int l = 0; l < 8; ++l) {
    float ax = 0.f, az = 0.f;
#pragma unroll
    for (int d = 0; d < 16; ++d) {
      float sv = yr[l * 16 + d];
      ax = fmaf(sv, Wi_t[d * 64 + ch], ax);
      az = fmaf(sv, Wi_t[d * 64 + 32 + ch], az);
    }
    xi[l] = ax; zg[l] = az;
  }
  float cwr[4];
#pragma unroll
  for (int k = 0; k < 4; ++k) cwr[k] = c1w_s[ch * 4 + k];
  const float cbr = c1b_s[ch];
  float xc[8];
#pragma unroll
  for (int l = 0; l < 8; ++l) {
    float a = fmaf(cwr[3], xi[l], cbr);
    if (l >= 1) a = fmaf(cwr[2], xi[l - 1], a);
    if (l >= 2) a = fmaf(cwr[1], xi[l - 2], a);
    if (l >= 3) a = fmaf(cwr[0], xi[l - 3], a);
    float sc = a * sigmoid_f(a);
    xc[l] = sc;
    xc_s[(s * 8 + l) * 32 + ch] = sc;
  }
  __syncthreads();
#pragma unroll
  for (int l = 0; l < 8; ++l) {
    const float* xr = &xc_s[(s * 8 + l) * 32];
    float a = 0.f;
#pragma unroll
    for (int d = 0; d < 32; ++d) a = fmaf(xr[d], Xp_t[d * 33 + ch], a);
    if (ch == 0)        dt0_s[s * 8 + l] = a;
    else if (ch <= 16)  B_s[(s * 8 + l) * 16 + (ch - 1)]  = a;
    else                C_s[(s * 8 + l) * 16 + (ch - 17)] = a;
    if (ch == 0) {
      float a2 = 0.f;
#pragma unroll
      for (int d = 0; d < 32; ++d) a2 = fmaf(xr[d], Xp_t[d * 33 + 32], a2);
      C_s[(s * 8 + l) * 16 + 15] = a2;
    }
  }
  __syncthreads();
  float A2r[16];
#pragma unroll
  for (int st = 0; st < 16; ++st) A2r[st] = A2_s[ch * 17 + st];
  const float dwv = dtw_s[ch], dbv = dtb_s[ch], Dv = D_s[ch];
  float hreg[16];
#pragma unroll
  for (int st = 0; st < 16; ++st) hreg[st] = 0.f;
#pragma unroll
  for (int l = 0; l < 8; ++l) {
    float pre = fmaf(dt0_s[s * 8 + l], dwv, dbv);
    float dtl = (pre > 20.f) ? pre : log1pf(__expf(pre));
    float dtxc = dtl * xc[l];
    const float* Br = &B_s[(s * 8 + l) * 16];
    const float* Cr = &C_s[(s * 8 + l) * 16];
    float yl = 0.f;
#pragma unroll
    for (int st = 0; st < 16; ++st) {
      float aa = exp2f(dtl * A2r[st]);
      float bb = dtxc * Br[st];
      hreg[st] = fmaf(aa, hreg[st], bb);
      yl = fmaf(hreg[st], Cr[st], yl);
    }
    float ymv = fmaf(Dv, xc[l], yl) * (zg[l] * sigmoid_f(zg[l]));
    ym_s[(s * 8 + l) * 32 + ch] = ymv;
  }
  __syncthreads();
  const int e  = ch & 15;
  const int lg = ch >> 4;
  const int n  = blockIdx.x * 8 + s;
  float ls = 0.f, lq = 0.f;
  float* mrow = m + (size_t)n * 128;
#pragma unroll
  for (int i = 0; i < 4; ++i) {
    int l = lg * 4 + i;
    const float* ymr = &ym_s[(s * 8 + l) * 32];
    float a = 0.f;
#pragma unroll
    for (int d = 0; d < 32; ++d) a = fmaf(ymr[d], Wo_t[d * 17 + e], a);
    mrow[l * 16 + e] = a;
    ls += a;
    lq = fmaf(a, a, lq);
  }
#pragma unroll
  for (int off = 32; off > 0; off >>= 1) {
    ls += __shfl_down(ls, off);
    lq += __shfl_down(lq, off);
  }
  const int wid = tid >> 6;
  if ((tid & 63) == 0) { red_s[wid * 2] = ls; red_s[wid * 2 + 1] = lq; }
  __syncthreads();
  if (tid == 0) {
    float S = red_s[0] + red_s[2] + red_s[4] + red_s[6];
    float Q = red_s[1] + red_s[3] + red_s[5] + red_s[7];
    int bb = n >> 14;
    int cc = (n >> 7) & 127;
    int gg = cc >> 5;
    atomicAdd(&stats[(bb * 4 + gg) * 2 + 0], S);
    atomicAdd(&stats[(bb * 4 + gg) * 2 + 1], Q);
  }
}

// =====================================================================
// K3: GroupNorm finalize + SiLU + residual (unchanged from R2).
// =====================================================================
__global__ __launch_bounds__(256) void gn_silu_k(
    const float* __restrict__ x,
    const float* __restrict__ gnw, const float* __restrict__ gnb,
    const float* __restrict__ stats, float* __restrict__ out) {
  const int idx0 = (blockIdx.x * 256 + threadIdx.x) * 4;
  const int bb = idx0 >> 21;
  const int cc = (idx0 >> 14) & 127;
  const int gg = cc >> 5;
  const float S = stats[(bb * 4 + gg) * 2 + 0];
  const float Q = stats[(bb * 4 + gg) * 2 + 1];
  const float inv  = 1.0f / 524288.0f;
  const float mu   = S * inv;
  const float var  = fmaf(Q, inv, -mu * mu);
  const float rstd = rsqrtf(var + 1e-5f);
  const float gw  = gnw[cc] * rstd;
  const float gb2 = gnb[cc] - mu * gw;

  float4 mv = *(const float4*)(out + idx0);
  float4 xv = *(const float4*)(x + idx0);
  float mvv[4] = { mv.x, mv.y, mv.z, mv.w };
  float xf[4]  = { xv.x, xv.y, xv.z, xv.w };
  float res[4];
#pragma unroll
  for (int j = 0; j < 4; ++j) {
    float nv = fmaf(mvv[j], gw, gb2);
    float sv = nv * sigmoid_f(nv);
    res[j] = xf[j] + sv;
  }
  *(float4*)(out + idx0) = make_float4(res[0], res[1], res[2], res[3]);
}

// =====================================================================
extern "C" void kernel_launch(void* const* d_in, const int* in_sizes, int n_in,
                              void* d_out, int out_size, void* d_ws, size_t ws_size,
                              hipStream_t stream) {
  const float* x     = (const float*)d_in[0];
  const float* convw = (const float*)d_in[1];
  const float* convb = (const float*)d_in[2];
  const float* gnw   = (const float*)d_in[3];
  const float* gnb   = (const float*)d_in[4];
  const float* winp  = (const float*)d_in[5];
  const float* c1w   = (const float*)d_in[6];
  const float* c1b   = (const float*)d_in[7];
  const float* xpw   = (const float*)d_in[8];
  const float* dtw   = (const float*)d_in[9];
  const float* dtb   = (const float*)d_in[10];
  const float* alog  = (const float*)d_in[11];
  const float* dvec  = (const float*)d_in[12];
  const float* wout  = (const float*)d_in[13];

  float*  y     = (float*)d_ws;                 // 16 MB
  float*  stats = y + 4194304;                  // 64 B
  USHORT* wrep  = (USHORT*)d_out;               // 295 KB, dead after conv;
  float*  m     = (float*)d_out;                // mamba overwrites ALL of d_out

  hipMemsetAsync(stats, 0, 16 * sizeof(float), stream);
  hipLaunchKernelGGL(prep_w_k, dim3(576), dim3(256), 0, stream, convw, wrep);
  hipLaunchKernelGGL(conv_mfma_k, dim3(512), dim3(256), 0, stream, x, wrep, convb, y);
  hipLaunchKernelGGL(mamba_k, dim3(4096), dim3(256), 0, stream,
                     y, winp, c1w, c1b, xpw, dtw, dtb, alog, dvec, wout, m, stats);
  hipLaunchKernelGGL(gn_silu_k, dim3(4096), dim3(256), 0, stream,
                     x, gnw, gnb, stats, (float*)d_out);
}